// Round 9
// baseline (766.791 us; speedup 1.0000x reference)
//
#include <hip/hip_runtime.h>

#define B_SZ 8192
#define IN_SZ 1024
#define G_SZ 100
#define F_SZ 128

using f32x4 = __attribute__((ext_vector_type(4))) float;
using s16x8 = __attribute__((ext_vector_type(8))) short;
typedef __bf16 bf16x8 __attribute__((ext_vector_type(8)));

__device__ __forceinline__ short cvt_bf16(float f) {      // HW RNE f32->bf16
    __bf16 h = (__bf16)f;
    return __builtin_bit_cast(short, h);
}
__device__ __forceinline__ float bfs2f(short s) {
    union { unsigned u; float f; } v; v.u = ((unsigned)(unsigned short)s) << 16;
    return v.f;
}

// LDS-only barrier: does NOT drain vmcnt, so prefetched global loads stay in
// flight across it (plain __syncthreads emits s_waitcnt vmcnt(0)).  All
// cross-wave deps at these points are LDS (bounce buffer / stat scratch).
__device__ __forceinline__ void bar_lds() {
    __builtin_amdgcn_sched_barrier(0);
    asm volatile("s_waitcnt lgkmcnt(0)" ::: "memory");
    __builtin_amdgcn_s_barrier();
    __builtin_amdgcn_sched_barrier(0);
}

// ---------------------------------------------------------------------------
// Gather: Ag[g][b][f] = bf16(x[b][uf[g*128+f]]).
// ---------------------------------------------------------------------------
__global__ __launch_bounds__(256) void k_gather(const float* __restrict__ x,
                                                const int* __restrict__ uf,
                                                unsigned short* __restrict__ Ag) {
    __shared__ __align__(16) unsigned short xrow[16][1032];
    const int t = threadIdx.x;
    const int b0 = blockIdx.x * 16;
    #pragma unroll
    for (int i = 0; i < 16; ++i) {
        int c4 = t + i * 256;
        int r = c4 >> 8;
        int cc = (c4 & 255) << 2;
        float4 v = *reinterpret_cast<const float4*>(&x[(size_t)(b0 + r) * IN_SZ + cc]);
        ushort4 o;
        o.x = (unsigned short)cvt_bf16(v.x); o.y = (unsigned short)cvt_bf16(v.y);
        o.z = (unsigned short)cvt_bf16(v.z); o.w = (unsigned short)cvt_bf16(v.w);
        *reinterpret_cast<ushort4*>(&xrow[r][cc]) = o;
    }
    __syncthreads();
    for (int i = 0; i < 200; ++i) {
        int c = t + i * 256;
        int ch = c & 31; int r = (c >> 5) & 15; int g = c >> 9;
        int4 id = *reinterpret_cast<const int4*>(&uf[g * F_SZ + ch * 4]);
        ushort4 o;
        o.x = xrow[r][id.x]; o.y = xrow[r][id.y]; o.z = xrow[r][id.z]; o.w = xrow[r][id.w];
        *reinterpret_cast<ushort4*>(&Ag[(((size_t)g * B_SZ + b0 + r) << 7) + ch * 4]) = o;
    }
}

// ---------------------------------------------------------------------------
// Pre-pack W (+bias at k==K_SRC when FOLD) into MFMA fragment order.
// ---------------------------------------------------------------------------
template<int K_SRC, int N_OUT, int NT, bool FOLD>
__device__ __forceinline__ void pack_one(int e, const float* __restrict__ W,
                                         const float* __restrict__ bias,
                                         unsigned short* __restrict__ P) {
    constexpr int EPG = 4 * NT * 64;
    int g = e / EPG; int r = e - g * EPG;
    int lane = r & 63; int nt = (r >> 6) % NT; int ks = r / (64 * NT);
    int n = nt * 16 + (lane & 15); int kb = ks * 32 + (lane >> 4) * 8;
    s16x8 v;
    #pragma unroll
    for (int j = 0; j < 8; ++j) {
        int k = kb + j; float val = 0.f;
        if (n < N_OUT) {
            if (k < K_SRC) val = W[((size_t)g * K_SRC + k) * N_OUT + n];
            else if (FOLD && k == K_SRC) val = bias[g * N_OUT + n];
        }
        v[j] = cvt_bf16(val);
    }
    *reinterpret_cast<s16x8*>(&P[(size_t)e * 8]) = v;
}

__global__ __launch_bounds__(256) void k_packW(
    const float* __restrict__ w0,
    const float* __restrict__ w1, const float* __restrict__ b1,
    const float* __restrict__ w2, const float* __restrict__ b2,
    unsigned short* __restrict__ p0, unsigned short* __restrict__ p1,
    unsigned short* __restrict__ p2) {
    int id = blockIdx.x * 256 + threadIdx.x;           // 460800 total
    if (id < 179200)       pack_one<128, 100, 7, false>(id, w0, nullptr, p0);
    else if (id < 358400)  pack_one<100, 100, 7, true >(id - 179200, w1, b1, p1);
    else                   pack_one<100,  50, 4, true >(id - 358400, w2, b2, p2);
}

// ---------------------------------------------------------------------------
// Per-group dense, bf16 MFMA 16x16x32.  Each block processes TWO consecutive
// 128-row m-tiles, software-pipelined: tile1's A-loads are issued right after
// tile0's acc is parked in LDS, and stay in flight across the (LDS-only)
// barriers and tile0's store loop.  BN stats accumulate in registers across
// both tiles (half the atomics).  W fragments from pre-packed table (L1-hot
// for tile1).  NOTE: launch_bounds (256,4); (256,8) spills acc (R5).
// ---------------------------------------------------------------------------
template<int K_SRC, int N_OUT, int NT, bool BN_IN, bool IS_LAST, bool HAS_BIAS>
__global__ __launch_bounds__(256, 4) void k_dense(
    const unsigned short* __restrict__ Ain,   // [G][B][K_SRC] bf16 row-major
    const unsigned short* __restrict__ Wf,    // [G][4*NT*64][8] packed
    const float* __restrict__ bias,           // only when HAS_BIAS
    const float* __restrict__ sa, const float* __restrict__ sb, // [G*128]
    unsigned short* __restrict__ Hout,        // [G][B][N_OUT] bf16
    float* __restrict__ pred,                 // [B][5000] f32
    float* __restrict__ ssum, float* __restrict__ ssq, // [G*100]
    const float* __restrict__ ow, float* __restrict__ out_acc)
{
    constexpr int EPG = 4 * NT * 64;
    __shared__ __align__(16) unsigned short LH[IS_LAST ? 16 : 128 * 104];
    __shared__ __align__(16) float LP[IS_LAST ? 128 * 52 : 16];
    __shared__ float ls1[IS_LAST ? 1 : NT * 16];
    __shared__ float ls2[IS_LAST ? 1 : NT * 16];

    const int t = threadIdx.x;
    const int g = blockIdx.x >> 5;
    const int mt0 = (blockIdx.x & 31) << 1;   // first tile (of 64 per group)
    const int m0_0 = mt0 << 7, m0_1 = (mt0 + 1) << 7;
    const int lane = t & 63, wid = t >> 6;
    const int lr = lane & 15, lg = lane >> 4;

    if constexpr (!IS_LAST) {
        if (t < NT * 16) { ls1[t] = 0.f; ls2[t] = 0.f; }
    }

    const unsigned short* wbase = Wf + ((size_t)g * EPG + lane) * 8;

    float rs1[NT] = {}, rs2[NT] = {};         // deferred BN-stat partials
    float bvn[NT];
    #pragma unroll
    for (int nt = 0; nt < NT; ++nt) {
        bvn[nt] = 0.f;
        if constexpr (HAS_BIAS) {
            int col = nt * 16 + lr;
            if (col < N_OUT) bvn[nt] = bias[g * N_OUT + col];
        }
    }

    auto load_a = [&](s16x8 (&a)[2][4], int m0) {
        if constexpr (K_SRC == 128) {
            const unsigned short* r0 = Ain + ((size_t)g * B_SZ + m0 + wid * 32 + lr) * 128;
            #pragma unroll
            for (int ks = 0; ks < 4; ++ks) {
                const int kb = ks * 32 + lg * 8;
                a[0][ks] = *reinterpret_cast<const s16x8*>(r0 + kb);
                a[1][ks] = *reinterpret_cast<const s16x8*>(r0 + 16 * 128 + kb);
            }
        } else {
            const unsigned short* r0 = Ain + ((size_t)g * B_SZ + m0 + wid * 32 + lr) * 100;
            #pragma unroll
            for (int ks = 0; ks < 3; ++ks) {
                const int kb = ks * 32 + lg * 8;
                #pragma unroll
                for (int h = 0; h < 2; ++h) {
                    reinterpret_cast<short4*>(&a[h][ks])[0] =
                        *reinterpret_cast<const short4*>(r0 + h * 16 * 100 + kb);
                    reinterpret_cast<short4*>(&a[h][ks])[1] =
                        *reinterpret_cast<const short4*>(r0 + h * 16 * 100 + kb + 4);
                }
            }
            a[0][3] = s16x8{}; a[1][3] = s16x8{};
            if (lg == 0) {
                reinterpret_cast<short4*>(&a[0][3])[0] =
                    *reinterpret_cast<const short4*>(r0 + 96);
                reinterpret_cast<short4*>(&a[1][3])[0] =
                    *reinterpret_cast<const short4*>(r0 + 16 * 100 + 96);
            }
        }
    };

    #define APP(vv, idx, s, o) { float f_ = bfs2f(vv[idx]) * (s) + (o); \
                                 vv[idx] = cvt_bf16(fmaxf(f_, 0.f)); }
    auto bn_a = [&](s16x8 (&a)[2][4]) {
        #pragma unroll
        for (int ks = 0; ks < 3; ++ks) {
            const int kb = ks * 32 + lg * 8;
            float4 S0 = *reinterpret_cast<const float4*>(&sa[g * 128 + kb]);
            float4 S1 = *reinterpret_cast<const float4*>(&sa[g * 128 + kb + 4]);
            float4 O0 = *reinterpret_cast<const float4*>(&sb[g * 128 + kb]);
            float4 O1 = *reinterpret_cast<const float4*>(&sb[g * 128 + kb + 4]);
            #pragma unroll
            for (int h = 0; h < 2; ++h) {
                APP(a[h][ks],0,S0.x,O0.x) APP(a[h][ks],1,S0.y,O0.y)
                APP(a[h][ks],2,S0.z,O0.z) APP(a[h][ks],3,S0.w,O0.w)
                APP(a[h][ks],4,S1.x,O1.x) APP(a[h][ks],5,S1.y,O1.y)
                APP(a[h][ks],6,S1.z,O1.z) APP(a[h][ks],7,S1.w,O1.w)
            }
        }
        if (lg == 0) {                 // tail channels 96..99 + bias slot 1.0
            float4 S0 = *reinterpret_cast<const float4*>(&sa[g * 128 + 96]);
            float4 O0 = *reinterpret_cast<const float4*>(&sb[g * 128 + 96]);
            #pragma unroll
            for (int h = 0; h < 2; ++h) {
                APP(a[h][3],0,S0.x,O0.x) APP(a[h][3],1,S0.y,O0.y)
                APP(a[h][3],2,S0.z,O0.z) APP(a[h][3],3,S0.w,O0.w)
                a[h][3][4] = (short)0x3F80;   // 1.0 -> bias row of W
            }
        }
    };
    #undef APP

    f32x4 acc[2][NT];
    auto mfma_a = [&](s16x8 (&a)[2][4]) {
        #pragma unroll
        for (int mi = 0; mi < 2; ++mi)
            #pragma unroll
            for (int nt = 0; nt < NT; ++nt)
                acc[mi][nt] = f32x4{};
        #pragma unroll
        for (int ks = 0; ks < 4; ++ks) {
            bf16x8 av0 = __builtin_bit_cast(bf16x8, a[0][ks]);
            bf16x8 av1 = __builtin_bit_cast(bf16x8, a[1][ks]);
            #pragma unroll
            for (int nt = 0; nt < NT; ++nt) {
                s16x8 b = *reinterpret_cast<const s16x8*>(wbase + (size_t)((ks * NT + nt) * 64) * 8);
                bf16x8 bv = __builtin_bit_cast(bf16x8, b);
                if constexpr (IS_LAST) {
                    acc[0][nt] = __builtin_amdgcn_mfma_f32_16x16x32_bf16(bv, av0, acc[0][nt], 0, 0, 0);
                    acc[1][nt] = __builtin_amdgcn_mfma_f32_16x16x32_bf16(bv, av1, acc[1][nt], 0, 0, 0);
                } else {
                    acc[0][nt] = __builtin_amdgcn_mfma_f32_16x16x32_bf16(av0, bv, acc[0][nt], 0, 0, 0);
                    acc[1][nt] = __builtin_amdgcn_mfma_f32_16x16x32_bf16(av1, bv, acc[1][nt], 0, 0, 0);
                }
            }
        }
    };

    // non-last helpers
    auto lh_write = [&]() {
        #pragma unroll
        for (int nt = 0; nt < NT; ++nt) {
            const int col = nt * 16 + lr;
            const bool valid = col < N_OUT;
            #pragma unroll
            for (int mi = 0; mi < 2; ++mi) {
                const int rloc = wid * 32 + mi * 16 + (lg << 2);
                #pragma unroll
                for (int r = 0; r < 4; ++r) {
                    float v = acc[mi][nt][r] + bvn[nt];
                    short hb = cvt_bf16(v);
                    float vq = bfs2f(hb);
                    rs1[nt] += vq; rs2[nt] += vq * vq;
                    if (valid) LH[(rloc + r) * 104 + col] = (unsigned short)hb;
                }
            }
        }
    };
    auto lh_store = [&](int m0) {
        #pragma unroll
        for (int i = 0; i < 13; ++i) {
            int e = t + i * 256;
            if (e < 3200) {
                int row = e / 25;
                int c4 = (e - row * 25) * 4;
                ushort4 v = *reinterpret_cast<const ushort4*>(&LH[row * 104 + c4]);
                *reinterpret_cast<ushort4*>(
                    Hout + ((size_t)g * B_SZ + m0 + row) * 100 + c4) = v;
            }
        }
    };

    // last-layer helpers
    auto lp_write_dot = [&](int m0) {
        #pragma unroll
        for (int mi = 0; mi < 2; ++mi) {
            const int bl = wid * 32 + mi * 16 + lr;
            float dp = 0.f;
            #pragma unroll
            for (int nt = 0; nt < NT; ++nt) {
                const int n0 = nt * 16 + (lg << 2);
                f32x4 v = acc[mi][nt];
                if (nt < 3) {
                    float2 w01 = *reinterpret_cast<const float2*>(&ow[g * N_OUT + n0]);
                    float2 w23 = *reinterpret_cast<const float2*>(&ow[g * N_OUT + n0 + 2]);
                    dp += v[0] * w01.x + v[1] * w01.y + v[2] * w23.x + v[3] * w23.y;
                    LP[bl * 52 + n0 + 0] = v[0]; LP[bl * 52 + n0 + 1] = v[1];
                    LP[bl * 52 + n0 + 2] = v[2]; LP[bl * 52 + n0 + 3] = v[3];
                } else if (lg == 0) {          // n0 = 48: n=48,49 valid
                    float2 w01 = *reinterpret_cast<const float2*>(&ow[g * N_OUT + n0]);
                    dp += v[0] * w01.x + v[1] * w01.y;
                    LP[bl * 52 + n0 + 0] = v[0]; LP[bl * 52 + n0 + 1] = v[1];
                }
            }
            dp += __shfl_xor(dp, 16); dp += __shfl_xor(dp, 32);
            if (lg == 0) atomicAdd(&out_acc[m0 + bl], dp);
        }
    };
    auto lp_store = [&](int m0) {
        #pragma unroll
        for (int i = 0; i < 13; ++i) {
            int e = t + i * 256;
            if (e < 3200) {
                int row = e / 25;
                int c2 = e - row * 25;
                float2 v = *reinterpret_cast<const float2*>(&LP[row * 52 + c2 * 2]);
                *reinterpret_cast<float2*>(
                    &pred[(size_t)(m0 + row) * 5000 + g * N_OUT + c2 * 2]) = v;
            }
        }
    };

    s16x8 aA[2][4], aB[2][4];

    // ---- tile 0 ----
    load_a(aA, m0_0);
    if constexpr (BN_IN) bn_a(aA);
    mfma_a(aA);
    if constexpr (!IS_LAST) {
        lh_write();                 // acc parked in LDS; acc/aA regs now dead
        load_a(aB, m0_1);           // prefetch: in flight across bar_lds+stores
        bar_lds();
        lh_store(m0_0);
        bar_lds();
        // ---- tile 1 ----
        if constexpr (BN_IN) bn_a(aB);
        mfma_a(aB);
        lh_write();
        bar_lds();
        lh_store(m0_1);
        // ---- deferred BN stats ----
        #pragma unroll
        for (int nt = 0; nt < NT; ++nt) {
            float s1 = rs1[nt], s2 = rs2[nt];
            s1 += __shfl_xor(s1, 16); s1 += __shfl_xor(s1, 32);
            s2 += __shfl_xor(s2, 16); s2 += __shfl_xor(s2, 32);
            const int col = nt * 16 + lr;
            if (col < N_OUT && lg == 0) {
                atomicAdd(&ls1[col], s1);
                atomicAdd(&ls2[col], s2);
            }
        }
        bar_lds();
        if (t < N_OUT) {
            atomicAdd(&ssum[g * N_OUT + t], ls1[t]);
            atomicAdd(&ssq[g * N_OUT + t], ls2[t]);
        }
    } else {
        lp_write_dot(m0_0);
        load_a(aB, m0_1);           // prefetch
        bar_lds();
        lp_store(m0_0);
        bar_lds();
        // ---- tile 1 ----
        if constexpr (BN_IN) bn_a(aB);
        mfma_a(aB);
        lp_write_dot(m0_1);
        bar_lds();
        lp_store(m0_1);
    }
}

// BN finalize -> per-channel scale/offset (128-stride, identity pads).
__global__ __launch_bounds__(256) void k_bnfin(const float* __restrict__ ssum,
                                               const float* __restrict__ ssq,
                                               const float* __restrict__ gamma,
                                               const float* __restrict__ beta,
                                               float* __restrict__ sa,
                                               float* __restrict__ sb) {
    int c = blockIdx.x * 256 + threadIdx.x;
    if (c < G_SZ * 128) {
        int g = c >> 7, ch = c & 127;
        float s, o;
        if (ch < 100) {
            float mean = ssum[g * 100 + ch] * (1.f / 8192.f);
            float var = ssq[g * 100 + ch] * (1.f / 8192.f) - mean * mean;
            s = rsqrtf(var + 1e-5f) * gamma[g * 100 + ch];
            o = beta[g * 100 + ch] - mean * s;
        } else { s = 1.f; o = 0.f; }
        sa[c] = s; sb[c] = o;
    }
}

__global__ __launch_bounds__(256) void k_sig(const float* __restrict__ out_acc,
                                             const float* __restrict__ ob,
                                             float* __restrict__ out) {
    int b = blockIdx.x * 256 + threadIdx.x;
    if (b < B_SZ) {
        float v = ob[0] + out_acc[b];
        out[b] = 1.f / (1.f + expf(-v));
    }
}

extern "C" void kernel_launch(void* const* d_in, const int* in_sizes, int n_in,
                              void* d_out, int out_size, void* d_ws, size_t ws_size,
                              hipStream_t stream) {
    const float* x      = (const float*)d_in[0];
    const int*   uf     = (const int*)d_in[1];
    const float* w0     = (const float*)d_in[2];
    const float* b0     = (const float*)d_in[3];
    const float* w1     = (const float*)d_in[4];
    const float* b1     = (const float*)d_in[5];
    const float* w2     = (const float*)d_in[6];
    const float* b2     = (const float*)d_in[7];
    const float* gamma0 = (const float*)d_in[8];
    const float* beta0  = (const float*)d_in[9];
    const float* gamma1 = (const float*)d_in[10];
    const float* beta1  = (const float*)d_in[11];
    const float* ow     = (const float*)d_in[12];
    const float* ob     = (const float*)d_in[13];

    char* ws = (char*)d_ws;
    const size_t AG_BYTES = (size_t)G_SZ * B_SZ * 128 * 2;  // 209,715,200
    unsigned short* Ag = (unsigned short*)ws;
    unsigned short* h1 = Ag;   // row-major [100][8192][100] bf16; aliases Ag
    float* stat = (float*)(ws + AG_BYTES);
    float* sum0    = stat;            // 10000
    float* ssq0    = stat + 10000;
    float* sum1    = stat + 20000;
    float* ssq1    = stat + 30000;
    float* out_acc = stat + 40000;    // 8192  (zeroed region ends at 48192)
    float* sa0     = stat + 48192;    // 12800 each, fully written by bnfin
    float* sb0     = stat + 60992;
    float* sa1     = stat + 73792;
    float* sb1     = stat + 86592;    // ends 99392 floats = 397,568 B

    unsigned short* p0 = (unsigned short*)(ws + AG_BYTES + 397568);
    unsigned short* p1 = p0 + (size_t)179200 * 8;   // 2,867,200 B each
    unsigned short* p2 = p1 + (size_t)179200 * 8;   // p2: 1,638,400 B

    // h0 row-major in d_out's pred region (dead before dense2 writes pred).
    unsigned short* h0 = (unsigned short*)((float*)d_out + B_SZ);
    float* pred = (float*)d_out + B_SZ;
    float* sig  = (float*)d_out;

    hipMemsetAsync(stat, 0, 48192 * sizeof(float), stream);

    k_packW<<<1800, 256, 0, stream>>>(w0, w1, b1, w2, b2, p0, p1, p2);
    k_gather<<<B_SZ / 16, 256, 0, stream>>>(x, uf, Ag);

    // dense0: K=128 in, bias in epilogue
    k_dense<128, 100, 7, false, false, true><<<3200, 256, 0, stream>>>(
        Ag, p0, b0, nullptr, nullptr, h0, nullptr, sum0, ssq0, nullptr, nullptr);
    k_bnfin<<<50, 256, 0, stream>>>(sum0, ssq0, gamma0, beta0, sa0, sb0);

    // dense1: K=100 in (BN+fold), row-major out
    k_dense<100, 100, 7, true, false, false><<<3200, 256, 0, stream>>>(
        h0, p1, nullptr, sa0, sb0, h1, nullptr, sum1, ssq1, nullptr, nullptr);
    k_bnfin<<<50, 256, 0, stream>>>(sum1, ssq1, gamma1, beta1, sa1, sb1);

    // dense2: K=100 in (BN+fold), pred + dot out
    k_dense<100, 50, 4, true, true, false><<<3200, 256, 0, stream>>>(
        h1, p2, nullptr, sa1, sb1, nullptr, pred, nullptr, nullptr, ow, out_acc);

    k_sig<<<32, 256, 0, stream>>>(out_acc, ob, sig);
}

// Round 10
// 448.652 us; speedup vs baseline: 1.7091x; 1.7091x over previous
//
#include <hip/hip_runtime.h>

#define B_SZ 8192
#define IN_SZ 1024
#define G_SZ 100
#define F_SZ 128

using f32x4 = __attribute__((ext_vector_type(4))) float;
using s16x8 = __attribute__((ext_vector_type(8))) short;
typedef __bf16 bf16x8 __attribute__((ext_vector_type(8)));

__device__ __forceinline__ short cvt_bf16(float f) {      // HW RNE f32->bf16
    __bf16 h = (__bf16)f;
    return __builtin_bit_cast(short, h);
}
__device__ __forceinline__ float bfs2f(short s) {
    union { unsigned u; float f; } v; v.u = ((unsigned)(unsigned short)s) << 16;
    return v.f;
}

// async global->LDS, 16B per lane; LDS dest = uniform base + lane*16
#define GLDS(gp, lp) __builtin_amdgcn_global_load_lds( \
    (const __attribute__((address_space(1))) void*)(gp), \
    (__attribute__((address_space(3))) void*)(lp), 16, 0, 0)

// ---------------------------------------------------------------------------
// Gather: Ag[g][b][.] = bf16(x[b][uf[g*128+f]]), stored PRE-SWIZZLED within
// each 256B row: 16B-chunk index c stored at position c^(b&7), so dense0's
// linear global_load_lds staging + XOR'd ds_read_b128 is bank-conflict-free
// (both-sides-or-neither, m173/m228c).
// ---------------------------------------------------------------------------
__global__ __launch_bounds__(256) void k_gather(const float* __restrict__ x,
                                                const int* __restrict__ uf,
                                                unsigned short* __restrict__ Ag) {
    __shared__ __align__(16) unsigned short xrow[16][1032];
    const int t = threadIdx.x;
    const int b0 = blockIdx.x * 16;
    #pragma unroll
    for (int i = 0; i < 16; ++i) {
        int c4 = t + i * 256;
        int r = c4 >> 8;
        int cc = (c4 & 255) << 2;
        float4 v = *reinterpret_cast<const float4*>(&x[(size_t)(b0 + r) * IN_SZ + cc]);
        ushort4 o;
        o.x = (unsigned short)cvt_bf16(v.x); o.y = (unsigned short)cvt_bf16(v.y);
        o.z = (unsigned short)cvt_bf16(v.z); o.w = (unsigned short)cvt_bf16(v.w);
        *reinterpret_cast<ushort4*>(&xrow[r][cc]) = o;
    }
    __syncthreads();
    for (int i = 0; i < 200; ++i) {
        int c = t + i * 256;
        int ch = c & 31; int r = (c >> 5) & 15; int g = c >> 9;
        int4 id = *reinterpret_cast<const int4*>(&uf[g * F_SZ + ch * 4]);
        ushort4 o;
        o.x = xrow[r][id.x]; o.y = xrow[r][id.y]; o.z = xrow[r][id.z]; o.w = xrow[r][id.w];
        const int b = b0 + r;
        // swizzled ushort index of this 8B chunk within the 256B row
        const int di = ((((ch >> 1) ^ (b & 7)) << 3) | ((ch & 1) << 2));
        *reinterpret_cast<ushort4*>(&Ag[(((size_t)g * B_SZ + b) << 7) + di]) = o;
    }
}

// ---------------------------------------------------------------------------
// Pre-pack W (+bias at k==K_SRC when FOLD) into MFMA fragment order.
// ---------------------------------------------------------------------------
template<int K_SRC, int N_OUT, int NT, bool FOLD>
__device__ __forceinline__ void pack_one(int e, const float* __restrict__ W,
                                         const float* __restrict__ bias,
                                         unsigned short* __restrict__ P) {
    constexpr int EPG = 4 * NT * 64;
    int g = e / EPG; int r = e - g * EPG;
    int lane = r & 63; int nt = (r >> 6) % NT; int ks = r / (64 * NT);
    int n = nt * 16 + (lane & 15); int kb = ks * 32 + (lane >> 4) * 8;
    s16x8 v;
    #pragma unroll
    for (int j = 0; j < 8; ++j) {
        int k = kb + j; float val = 0.f;
        if (n < N_OUT) {
            if (k < K_SRC) val = W[((size_t)g * K_SRC + k) * N_OUT + n];
            else if (FOLD && k == K_SRC) val = bias[g * N_OUT + n];
        }
        v[j] = cvt_bf16(val);
    }
    *reinterpret_cast<s16x8*>(&P[(size_t)e * 8]) = v;
}

__global__ __launch_bounds__(256) void k_packW(
    const float* __restrict__ w0,
    const float* __restrict__ w1, const float* __restrict__ b1,
    const float* __restrict__ w2, const float* __restrict__ b2,
    unsigned short* __restrict__ p0, unsigned short* __restrict__ p1,
    unsigned short* __restrict__ p2) {
    int id = blockIdx.x * 256 + threadIdx.x;           // 460800 total
    if (id < 179200)       pack_one<128, 100, 7, false>(id, w0, nullptr, p0);
    else if (id < 358400)  pack_one<100, 100, 7, true >(id - 179200, w1, b1, p1);
    else                   pack_one<100,  50, 4, true >(id - 358400, w2, b2, p2);
}

// ---------------------------------------------------------------------------
// Per-group dense, bf16 MFMA 16x16x32, ONE 128-row tile per block (R8 base).
//  - A tile staged LINEARLY into LDS via global_load_lds dwordx4 (contiguous
//    25.6/32KB -> minimal HBM transactions), fragments then ds_read from LDS.
//    dense0 reads with XOR swizzle matching k_gather's pre-swizzled layout;
//    dense1/2 rows (200B stride = bank-stride 18) are conflict-free linear.
//  - A-stage LDS is dead after fragment reads -> LH/LP bounce ALIASES it
//    (the existing __syncthreads separates the phases).
//  - W fragments per-lane from pre-packed table (L2-hot).
//  - BN stats: shfl -> LDS -> 1 global atomic/channel/block.
//  - IS_LAST: swapped mfma(W,A) -> D[n][b]; pred bounce + out_weight dot.
//  NOTE: launch_bounds (256,4); (256,8) caps VGPR at 64 -> acc spills (R5).
//        ONE tile in flight only: 2-tile pipelining spills (R9, 502MB scratch).
// ---------------------------------------------------------------------------
template<int K_SRC, int N_OUT, int NT, bool BN_IN, bool IS_LAST, bool HAS_BIAS>
__global__ __launch_bounds__(256, 4) void k_dense(
    const unsigned short* __restrict__ Ain,   // [G][B][K_SRC] bf16 (d0: swz)
    const unsigned short* __restrict__ Wf,    // [G][4*NT*64][8] packed
    const float* __restrict__ bias,           // only when HAS_BIAS
    const float* __restrict__ sa, const float* __restrict__ sb, // [G*128]
    unsigned short* __restrict__ Hout,        // [G][B][N_OUT] bf16
    float* __restrict__ pred,                 // [B][5000] f32
    float* __restrict__ ssum, float* __restrict__ ssq, // [G*100]
    const float* __restrict__ ow, float* __restrict__ out_acc)
{
    constexpr int EPG = 4 * NT * 64;
    constexpr int TILE_BYTES = 128 * K_SRC * 2;               // 32768 / 25600
    constexpr int BOUNCE = IS_LAST ? 128 * 52 * 4 : 128 * 104 * 2;  // 26624
    constexpr int UBYTES = TILE_BYTES > BOUNCE ? TILE_BYTES : BOUNCE;
    __shared__ __align__(16) unsigned char U[UBYTES];
    __shared__ float ls1[IS_LAST ? 1 : NT * 16];
    __shared__ float ls2[IS_LAST ? 1 : NT * 16];

    const int t = threadIdx.x;
    const int g = blockIdx.x >> 6;
    const int m0 = (blockIdx.x & 63) << 7;
    const int lane = t & 63, wid = t >> 6;
    const int lr = lane & 15, lg = lane >> 4;

    if constexpr (!IS_LAST) {
        if (t < NT * 16) { ls1[t] = 0.f; ls2[t] = 0.f; }
    }

    // ---- stage A tile (linear, async) ----
    constexpr int NI = TILE_BYTES / 1024;                     // 32 / 25
    const char* sbp = (const char*)(Ain + ((size_t)g * B_SZ + m0) * K_SRC);
    #pragma unroll
    for (int ji = 0; ji < (NI + 3) / 4; ++ji) {
        int i = ji * 4 + wid;                                 // wave-uniform
        if (i < NI) GLDS(sbp + i * 1024 + lane * 16, U + i * 1024);
    }
    __syncthreads();                                          // stage complete

    const unsigned short* wbase = Wf + ((size_t)g * EPG + lane) * 8;

    // ---- fragments from LDS ----
    s16x8 a[2][4];
    {
        const unsigned char* asb = U;
        const int row0 = wid * 32 + lr, row1 = row0 + 16;
        if constexpr (K_SRC == 128) {                         // swizzled rows
            #pragma unroll
            for (int ks = 0; ks < 4; ++ks) {
                const int c16 = ks * 4 + lg;
                a[0][ks] = *reinterpret_cast<const s16x8*>(
                    asb + row0 * 256 + ((c16 ^ (row0 & 7)) << 4));
                a[1][ks] = *reinterpret_cast<const s16x8*>(
                    asb + row1 * 256 + ((c16 ^ (row1 & 7)) << 4));
            }
        } else {                                              // K=100 linear
            const int rb0 = row0 * 200, rb1 = row1 * 200;
            #pragma unroll
            for (int ks = 0; ks < 3; ++ks) {
                const int kb2 = (ks * 32 + lg * 8) * 2;
                reinterpret_cast<short4*>(&a[0][ks])[0] =
                    *reinterpret_cast<const short4*>(asb + rb0 + kb2);
                reinterpret_cast<short4*>(&a[0][ks])[1] =
                    *reinterpret_cast<const short4*>(asb + rb0 + kb2 + 8);
                reinterpret_cast<short4*>(&a[1][ks])[0] =
                    *reinterpret_cast<const short4*>(asb + rb1 + kb2);
                reinterpret_cast<short4*>(&a[1][ks])[1] =
                    *reinterpret_cast<const short4*>(asb + rb1 + kb2 + 8);
            }
            a[0][3] = s16x8{}; a[1][3] = s16x8{};
            if (lg == 0) {
                reinterpret_cast<short4*>(&a[0][3])[0] =
                    *reinterpret_cast<const short4*>(asb + rb0 + 192);
                reinterpret_cast<short4*>(&a[1][3])[0] =
                    *reinterpret_cast<const short4*>(asb + rb1 + 192);
            }
        }
    }

    #define APP(vv, idx, s, o) { float f_ = bfs2f(vv[idx]) * (s) + (o); \
                                 vv[idx] = cvt_bf16(fmaxf(f_, 0.f)); }
    if constexpr (BN_IN) {
        #pragma unroll
        for (int ks = 0; ks < 3; ++ks) {
            const int kb = ks * 32 + lg * 8;
            float4 S0 = *reinterpret_cast<const float4*>(&sa[g * 128 + kb]);
            float4 S1 = *reinterpret_cast<const float4*>(&sa[g * 128 + kb + 4]);
            float4 O0 = *reinterpret_cast<const float4*>(&sb[g * 128 + kb]);
            float4 O1 = *reinterpret_cast<const float4*>(&sb[g * 128 + kb + 4]);
            #pragma unroll
            for (int h = 0; h < 2; ++h) {
                APP(a[h][ks],0,S0.x,O0.x) APP(a[h][ks],1,S0.y,O0.y)
                APP(a[h][ks],2,S0.z,O0.z) APP(a[h][ks],3,S0.w,O0.w)
                APP(a[h][ks],4,S1.x,O1.x) APP(a[h][ks],5,S1.y,O1.y)
                APP(a[h][ks],6,S1.z,O1.z) APP(a[h][ks],7,S1.w,O1.w)
            }
        }
        if (lg == 0) {                 // tail channels 96..99 + bias slot 1.0
            float4 S0 = *reinterpret_cast<const float4*>(&sa[g * 128 + 96]);
            float4 O0 = *reinterpret_cast<const float4*>(&sb[g * 128 + 96]);
            #pragma unroll
            for (int h = 0; h < 2; ++h) {
                APP(a[h][3],0,S0.x,O0.x) APP(a[h][3],1,S0.y,O0.y)
                APP(a[h][3],2,S0.z,O0.z) APP(a[h][3],3,S0.w,O0.w)
                a[h][3][4] = (short)0x3F80;   // 1.0 -> bias row of W
            }
        }
    }
    #undef APP

    // ---- MFMA ----
    f32x4 acc[2][NT] = {};
    #pragma unroll
    for (int ks = 0; ks < 4; ++ks) {
        bf16x8 av0 = __builtin_bit_cast(bf16x8, a[0][ks]);
        bf16x8 av1 = __builtin_bit_cast(bf16x8, a[1][ks]);
        #pragma unroll
        for (int nt = 0; nt < NT; ++nt) {
            s16x8 b = *reinterpret_cast<const s16x8*>(wbase + (size_t)((ks * NT + nt) * 64) * 8);
            bf16x8 bv = __builtin_bit_cast(bf16x8, b);
            if constexpr (IS_LAST) {
                acc[0][nt] = __builtin_amdgcn_mfma_f32_16x16x32_bf16(bv, av0, acc[0][nt], 0, 0, 0);
                acc[1][nt] = __builtin_amdgcn_mfma_f32_16x16x32_bf16(bv, av1, acc[1][nt], 0, 0, 0);
            } else {
                acc[0][nt] = __builtin_amdgcn_mfma_f32_16x16x32_bf16(av0, bv, acc[0][nt], 0, 0, 0);
                acc[1][nt] = __builtin_amdgcn_mfma_f32_16x16x32_bf16(av1, bv, acc[1][nt], 0, 0, 0);
            }
        }
    }

    // ---- epilogue (bounce buffer aliases the dead A-stage region) ----
    if constexpr (!IS_LAST) {
        unsigned short* LH = (unsigned short*)U;
        __syncthreads();               // all A ds_reads consumed; LH free
        #pragma unroll
        for (int nt = 0; nt < NT; ++nt) {
            const int col = nt * 16 + lr;
            const bool valid = col < N_OUT;
            float bv = 0.f;
            if constexpr (HAS_BIAS) bv = valid ? bias[g * N_OUT + col] : 0.f;
            float s1 = 0.f, s2 = 0.f;
            #pragma unroll
            for (int mi = 0; mi < 2; ++mi) {
                const int rloc = wid * 32 + mi * 16 + (lg << 2);
                #pragma unroll
                for (int r = 0; r < 4; ++r) {
                    float v = acc[mi][nt][r] + bv;
                    short hb = cvt_bf16(v);
                    float vq = bfs2f(hb);
                    s1 += vq; s2 += vq * vq;
                    if (valid) LH[(rloc + r) * 104 + col] = (unsigned short)hb;
                }
            }
            s1 += __shfl_xor(s1, 16); s1 += __shfl_xor(s1, 32);
            s2 += __shfl_xor(s2, 16); s2 += __shfl_xor(s2, 32);
            if (valid && lg == 0) {
                atomicAdd(&ls1[col], s1);
                atomicAdd(&ls2[col], s2);
            }
        }
        __syncthreads();
        if (t < N_OUT) {
            atomicAdd(&ssum[g * N_OUT + t], ls1[t]);
            atomicAdd(&ssq[g * N_OUT + t], ls2[t]);
        }
        #pragma unroll
        for (int i = 0; i < 13; ++i) {
            int e = t + i * 256;
            if (e < 3200) {
                int row = e / 25;
                int c4 = (e - row * 25) * 4;
                ushort4 v = *reinterpret_cast<const ushort4*>(&LH[row * 104 + c4]);
                *reinterpret_cast<ushort4*>(
                    Hout + ((size_t)g * B_SZ + m0 + row) * 100 + c4) = v;
            }
        }
    } else {
        float* LP = (float*)U;
        __syncthreads();               // A ds_reads done; LP free
        #pragma unroll
        for (int mi = 0; mi < 2; ++mi) {
            const int bl = wid * 32 + mi * 16 + lr;
            float dp = 0.f;
            #pragma unroll
            for (int nt = 0; nt < NT; ++nt) {
                const int n0 = nt * 16 + (lg << 2);
                f32x4 v = acc[mi][nt];
                if (nt < 3) {
                    float2 w01 = *reinterpret_cast<const float2*>(&ow[g * N_OUT + n0]);
                    float2 w23 = *reinterpret_cast<const float2*>(&ow[g * N_OUT + n0 + 2]);
                    dp += v[0] * w01.x + v[1] * w01.y + v[2] * w23.x + v[3] * w23.y;
                    LP[bl * 52 + n0 + 0] = v[0]; LP[bl * 52 + n0 + 1] = v[1];
                    LP[bl * 52 + n0 + 2] = v[2]; LP[bl * 52 + n0 + 3] = v[3];
                } else if (lg == 0) {          // n0 = 48: n=48,49 valid
                    float2 w01 = *reinterpret_cast<const float2*>(&ow[g * N_OUT + n0]);
                    dp += v[0] * w01.x + v[1] * w01.y;
                    LP[bl * 52 + n0 + 0] = v[0]; LP[bl * 52 + n0 + 1] = v[1];
                }
            }
            dp += __shfl_xor(dp, 16); dp += __shfl_xor(dp, 32);
            if (lg == 0) atomicAdd(&out_acc[m0 + bl], dp);
        }
        __syncthreads();
        #pragma unroll
        for (int i = 0; i < 13; ++i) {
            int e = t + i * 256;
            if (e < 3200) {
                int row = e / 25;
                int c2 = e - row * 25;
                float2 v = *reinterpret_cast<const float2*>(&LP[row * 52 + c2 * 2]);
                *reinterpret_cast<float2*>(
                    &pred[(size_t)(m0 + row) * 5000 + g * N_OUT + c2 * 2]) = v;
            }
        }
    }
}

// BN finalize -> per-channel scale/offset (128-stride, identity pads).
__global__ __launch_bounds__(256) void k_bnfin(const float* __restrict__ ssum,
                                               const float* __restrict__ ssq,
                                               const float* __restrict__ gamma,
                                               const float* __restrict__ beta,
                                               float* __restrict__ sa,
                                               float* __restrict__ sb) {
    int c = blockIdx.x * 256 + threadIdx.x;
    if (c < G_SZ * 128) {
        int g = c >> 7, ch = c & 127;
        float s, o;
        if (ch < 100) {
            float mean = ssum[g * 100 + ch] * (1.f / 8192.f);
            float var = ssq[g * 100 + ch] * (1.f / 8192.f) - mean * mean;
            s = rsqrtf(var + 1e-5f) * gamma[g * 100 + ch];
            o = beta[g * 100 + ch] - mean * s;
        } else { s = 1.f; o = 0.f; }
        sa[c] = s; sb[c] = o;
    }
}

__global__ __launch_bounds__(256) void k_sig(const float* __restrict__ out_acc,
                                             const float* __restrict__ ob,
                                             float* __restrict__ out) {
    int b = blockIdx.x * 256 + threadIdx.x;
    if (b < B_SZ) {
        float v = ob[0] + out_acc[b];
        out[b] = 1.f / (1.f + expf(-v));
    }
}

extern "C" void kernel_launch(void* const* d_in, const int* in_sizes, int n_in,
                              void* d_out, int out_size, void* d_ws, size_t ws_size,
                              hipStream_t stream) {
    const float* x      = (const float*)d_in[0];
    const int*   uf     = (const int*)d_in[1];
    const float* w0     = (const float*)d_in[2];
    const float* b0     = (const float*)d_in[3];
    const float* w1     = (const float*)d_in[4];
    const float* b1     = (const float*)d_in[5];
    const float* w2     = (const float*)d_in[6];
    const float* b2     = (const float*)d_in[7];
    const float* gamma0 = (const float*)d_in[8];
    const float* beta0  = (const float*)d_in[9];
    const float* gamma1 = (const float*)d_in[10];
    const float* beta1  = (const float*)d_in[11];
    const float* ow     = (const float*)d_in[12];
    const float* ob     = (const float*)d_in[13];

    char* ws = (char*)d_ws;
    const size_t AG_BYTES = (size_t)G_SZ * B_SZ * 128 * 2;  // 209,715,200
    unsigned short* Ag = (unsigned short*)ws;
    unsigned short* h1 = Ag;   // row-major [100][8192][100] bf16; aliases Ag
    float* stat = (float*)(ws + AG_BYTES);
    float* sum0    = stat;            // 10000
    float* ssq0    = stat + 10000;
    float* sum1    = stat + 20000;
    float* ssq1    = stat + 30000;
    float* out_acc = stat + 40000;    // 8192  (zeroed region ends at 48192)
    float* sa0     = stat + 48192;    // 12800 each, fully written by bnfin
    float* sb0     = stat + 60992;
    float* sa1     = stat + 73792;
    float* sb1     = stat + 86592;    // ends 99392 floats = 397,568 B

    unsigned short* p0 = (unsigned short*)(ws + AG_BYTES + 397568);
    unsigned short* p1 = p0 + (size_t)179200 * 8;   // 2,867,200 B each
    unsigned short* p2 = p1 + (size_t)179200 * 8;   // p2: 1,638,400 B

    // h0 row-major in d_out's pred region (dead before dense2 writes pred).
    unsigned short* h0 = (unsigned short*)((float*)d_out + B_SZ);
    float* pred = (float*)d_out + B_SZ;
    float* sig  = (float*)d_out;

    hipMemsetAsync(stat, 0, 48192 * sizeof(float), stream);

    k_packW<<<1800, 256, 0, stream>>>(w0, w1, b1, w2, b2, p0, p1, p2);
    k_gather<<<B_SZ / 16, 256, 0, stream>>>(x, uf, Ag);

    // dense0: K=128 in (pre-swizzled Ag), bias in epilogue
    k_dense<128, 100, 7, false, false, true><<<6400, 256, 0, stream>>>(
        Ag, p0, b0, nullptr, nullptr, h0, nullptr, sum0, ssq0, nullptr, nullptr);
    k_bnfin<<<50, 256, 0, stream>>>(sum0, ssq0, gamma0, beta0, sa0, sb0);

    // dense1: K=100 in (BN+fold), row-major out
    k_dense<100, 100, 7, true, false, false><<<6400, 256, 0, stream>>>(
        h0, p1, nullptr, sa0, sb0, h1, nullptr, sum1, ssq1, nullptr, nullptr);
    k_bnfin<<<50, 256, 0, stream>>>(sum1, ssq1, gamma1, beta1, sa1, sb1);

    // dense2: K=100 in (BN+fold), pred + dot out
    k_dense<100, 50, 4, true, true, false><<<6400, 256, 0, stream>>>(
        h1, p2, nullptr, sa1, sb1, nullptr, pred, nullptr, nullptr, ow, out_acc);

    k_sig<<<32, 256, 0, stream>>>(out_acc, ob, sig);
}

// Round 11
// 424.315 us; speedup vs baseline: 1.8071x; 1.0574x over previous
//
#include <hip/hip_runtime.h>

#define B_SZ 8192
#define IN_SZ 1024
#define G_SZ 100
#define F_SZ 128

using f32x4 = __attribute__((ext_vector_type(4))) float;
using s16x8 = __attribute__((ext_vector_type(8))) short;
typedef __bf16 bf16x8 __attribute__((ext_vector_type(8)));

__device__ __forceinline__ short cvt_bf16(float f) {      // HW RNE f32->bf16
    __bf16 h = (__bf16)f;
    return __builtin_bit_cast(short, h);
}
__device__ __forceinline__ float bfs2f(short s) {
    union { unsigned u; float f; } v; v.u = ((unsigned)(unsigned short)s) << 16;
    return v.f;
}

// ---------------------------------------------------------------------------
// Gather: Ag[g][b][f] = bf16(x[b][uf[g*128+f]])  (plain row-major layout).
// ---------------------------------------------------------------------------
__global__ __launch_bounds__(256) void k_gather(const float* __restrict__ x,
                                                const int* __restrict__ uf,
                                                unsigned short* __restrict__ Ag) {
    __shared__ __align__(16) unsigned short xrow[16][1032];
    const int t = threadIdx.x;
    const int b0 = blockIdx.x * 16;
    #pragma unroll
    for (int i = 0; i < 16; ++i) {
        int c4 = t + i * 256;
        int r = c4 >> 8;
        int cc = (c4 & 255) << 2;
        float4 v = *reinterpret_cast<const float4*>(&x[(size_t)(b0 + r) * IN_SZ + cc]);
        ushort4 o;
        o.x = (unsigned short)cvt_bf16(v.x); o.y = (unsigned short)cvt_bf16(v.y);
        o.z = (unsigned short)cvt_bf16(v.z); o.w = (unsigned short)cvt_bf16(v.w);
        *reinterpret_cast<ushort4*>(&xrow[r][cc]) = o;
    }
    __syncthreads();
    for (int i = 0; i < 200; ++i) {
        int c = t + i * 256;
        int ch = c & 31; int r = (c >> 5) & 15; int g = c >> 9;
        int4 id = *reinterpret_cast<const int4*>(&uf[g * F_SZ + ch * 4]);
        ushort4 o;
        o.x = xrow[r][id.x]; o.y = xrow[r][id.y]; o.z = xrow[r][id.z]; o.w = xrow[r][id.w];
        *reinterpret_cast<ushort4*>(&Ag[(((size_t)g * B_SZ + b0 + r) << 7) + ch * 4]) = o;
    }
}

// ---------------------------------------------------------------------------
// Pre-pack W (+bias at k==K_SRC when FOLD) into MFMA fragment order.
// ---------------------------------------------------------------------------
template<int K_SRC, int N_OUT, int NT, bool FOLD>
__device__ __forceinline__ void pack_one(int e, const float* __restrict__ W,
                                         const float* __restrict__ bias,
                                         unsigned short* __restrict__ P) {
    constexpr int EPG = 4 * NT * 64;
    int g = e / EPG; int r = e - g * EPG;
    int lane = r & 63; int nt = (r >> 6) % NT; int ks = r / (64 * NT);
    int n = nt * 16 + (lane & 15); int kb = ks * 32 + (lane >> 4) * 8;
    s16x8 v;
    #pragma unroll
    for (int j = 0; j < 8; ++j) {
        int k = kb + j; float val = 0.f;
        if (n < N_OUT) {
            if (k < K_SRC) val = W[((size_t)g * K_SRC + k) * N_OUT + n];
            else if (FOLD && k == K_SRC) val = bias[g * N_OUT + n];
        }
        v[j] = cvt_bf16(val);
    }
    *reinterpret_cast<s16x8*>(&P[(size_t)e * 8]) = v;
}

__global__ __launch_bounds__(256) void k_packW(
    const float* __restrict__ w0,
    const float* __restrict__ w1, const float* __restrict__ b1,
    const float* __restrict__ w2, const float* __restrict__ b2,
    unsigned short* __restrict__ p0, unsigned short* __restrict__ p1,
    unsigned short* __restrict__ p2) {
    int id = blockIdx.x * 256 + threadIdx.x;           // 460800 total
    if (id < 179200)       pack_one<128, 100, 7, false>(id, w0, nullptr, p0);
    else if (id < 358400)  pack_one<100, 100, 7, true >(id - 179200, w1, b1, p1);
    else                   pack_one<100,  50, 4, true >(id - 358400, w2, b2, p2);
}

// ---------------------------------------------------------------------------
// Per-group dense, bf16 MFMA 16x16x32, ONE 128-row tile per block.
//  - A fragments loaded directly from global (R8 path — measured identical to
//    LDS-staged, and frees LDS).  W fragments per-lane from packed table.
//  - Epilogue bounce SPLIT INTO TWO 64-ROW PHASES (waves 0/1 park -> all
//    store -> waves 2/3 park -> all store): LDS 27.6KB -> ~14.3KB so
//    8 blocks/CU (32 waves) become resident.  THE OCCUPANCY LEVER.
//  - BN stats deferred in registers, one shfl+LDS+global-atomic pass at end.
//  NOTE: launch_bounds (256,4); (256,8) caps VGPR at 64 -> acc spills (R5).
//        ONE tile in flight: 2-tile pipelining spills (R9, 502MB scratch).
// ---------------------------------------------------------------------------
template<int K_SRC, int N_OUT, int NT, bool BN_IN, bool IS_LAST, bool HAS_BIAS>
__global__ __launch_bounds__(256, 4) void k_dense(
    const unsigned short* __restrict__ Ain,   // [G][B][K_SRC] bf16 row-major
    const unsigned short* __restrict__ Wf,    // [G][4*NT*64][8] packed
    const float* __restrict__ bias,           // only when HAS_BIAS
    const float* __restrict__ sa, const float* __restrict__ sb, // [G*128]
    unsigned short* __restrict__ Hout,        // [G][B][N_OUT] bf16
    float* __restrict__ pred,                 // [B][5000] f32
    float* __restrict__ ssum, float* __restrict__ ssq, // [G*100]
    const float* __restrict__ ow, float* __restrict__ out_acc)
{
    constexpr int EPG = 4 * NT * 64;
    // 64-row half-tile bounce: 64*104*2 = 13312 B (u16) / 64*52*4 (f32) same.
    __shared__ __align__(16) unsigned char U[13312];
    __shared__ float ls1[IS_LAST ? 1 : NT * 16];
    __shared__ float ls2[IS_LAST ? 1 : NT * 16];

    const int t = threadIdx.x;
    const int g = blockIdx.x >> 6;
    const int m0 = (blockIdx.x & 63) << 7;
    const int lane = t & 63, wid = t >> 6;
    const int lr = lane & 15, lg = lane >> 4;

    if constexpr (!IS_LAST) {
        if (t < NT * 16) { ls1[t] = 0.f; ls2[t] = 0.f; }
    }

    const unsigned short* wbase = Wf + ((size_t)g * EPG + lane) * 8;

    // ---- A fragments: all 8 issued up front (direct global) ----
    s16x8 a[2][4];
    if constexpr (K_SRC == 128) {
        const unsigned short* r0 = Ain + ((size_t)g * B_SZ + m0 + wid * 32 + lr) * 128;
        #pragma unroll
        for (int ks = 0; ks < 4; ++ks) {
            const int kb = ks * 32 + lg * 8;
            a[0][ks] = *reinterpret_cast<const s16x8*>(r0 + kb);
            a[1][ks] = *reinterpret_cast<const s16x8*>(r0 + 16 * 128 + kb);
        }
    } else {  // K_SRC == 100
        const unsigned short* r0 = Ain + ((size_t)g * B_SZ + m0 + wid * 32 + lr) * 100;
        #pragma unroll
        for (int ks = 0; ks < 3; ++ks) {
            const int kb = ks * 32 + lg * 8;
            #pragma unroll
            for (int h = 0; h < 2; ++h) {
                reinterpret_cast<short4*>(&a[h][ks])[0] =
                    *reinterpret_cast<const short4*>(r0 + h * 16 * 100 + kb);
                reinterpret_cast<short4*>(&a[h][ks])[1] =
                    *reinterpret_cast<const short4*>(r0 + h * 16 * 100 + kb + 4);
            }
        }
        a[0][3] = s16x8{}; a[1][3] = s16x8{};
        if (lg == 0) {
            reinterpret_cast<short4*>(&a[0][3])[0] =
                *reinterpret_cast<const short4*>(r0 + 96);
            reinterpret_cast<short4*>(&a[1][3])[0] =
                *reinterpret_cast<const short4*>(r0 + 16 * 100 + 96);
        }
    }

    #define APP(vv, idx, s, o) { float f_ = bfs2f(vv[idx]) * (s) + (o); \
                                 vv[idx] = cvt_bf16(fmaxf(f_, 0.f)); }
    if constexpr (BN_IN) {
        #pragma unroll
        for (int ks = 0; ks < 3; ++ks) {
            const int kb = ks * 32 + lg * 8;
            float4 S0 = *reinterpret_cast<const float4*>(&sa[g * 128 + kb]);
            float4 S1 = *reinterpret_cast<const float4*>(&sa[g * 128 + kb + 4]);
            float4 O0 = *reinterpret_cast<const float4*>(&sb[g * 128 + kb]);
            float4 O1 = *reinterpret_cast<const float4*>(&sb[g * 128 + kb + 4]);
            #pragma unroll
            for (int h = 0; h < 2; ++h) {
                APP(a[h][ks],0,S0.x,O0.x) APP(a[h][ks],1,S0.y,O0.y)
                APP(a[h][ks],2,S0.z,O0.z) APP(a[h][ks],3,S0.w,O0.w)
                APP(a[h][ks],4,S1.x,O1.x) APP(a[h][ks],5,S1.y,O1.y)
                APP(a[h][ks],6,S1.z,O1.z) APP(a[h][ks],7,S1.w,O1.w)
            }
        }
        if (lg == 0) {                 // tail channels 96..99 + bias slot 1.0
            float4 S0 = *reinterpret_cast<const float4*>(&sa[g * 128 + 96]);
            float4 O0 = *reinterpret_cast<const float4*>(&sb[g * 128 + 96]);
            #pragma unroll
            for (int h = 0; h < 2; ++h) {
                APP(a[h][3],0,S0.x,O0.x) APP(a[h][3],1,S0.y,O0.y)
                APP(a[h][3],2,S0.z,O0.z) APP(a[h][3],3,S0.w,O0.w)
                a[h][3][4] = (short)0x3F80;   // 1.0 -> bias row of W
            }
        }
    }
    #undef APP

    // ---- MFMA ----
    f32x4 acc[2][NT] = {};
    #pragma unroll
    for (int ks = 0; ks < 4; ++ks) {
        bf16x8 av0 = __builtin_bit_cast(bf16x8, a[0][ks]);
        bf16x8 av1 = __builtin_bit_cast(bf16x8, a[1][ks]);
        #pragma unroll
        for (int nt = 0; nt < NT; ++nt) {
            s16x8 b = *reinterpret_cast<const s16x8*>(wbase + (size_t)((ks * NT + nt) * 64) * 8);
            bf16x8 bv = __builtin_bit_cast(bf16x8, b);
            if constexpr (IS_LAST) {
                acc[0][nt] = __builtin_amdgcn_mfma_f32_16x16x32_bf16(bv, av0, acc[0][nt], 0, 0, 0);
                acc[1][nt] = __builtin_amdgcn_mfma_f32_16x16x32_bf16(bv, av1, acc[1][nt], 0, 0, 0);
            } else {
                acc[0][nt] = __builtin_amdgcn_mfma_f32_16x16x32_bf16(av0, bv, acc[0][nt], 0, 0, 0);
                acc[1][nt] = __builtin_amdgcn_mfma_f32_16x16x32_bf16(av1, bv, acc[1][nt], 0, 0, 0);
            }
        }
    }

    // ---- epilogue: two 64-row phases through the half-size bounce ----
    if constexpr (!IS_LAST) {
        unsigned short* LH = (unsigned short*)U;
        float rs1[NT] = {}, rs2[NT] = {};
        float bvn[NT];
        #pragma unroll
        for (int nt = 0; nt < NT; ++nt) {
            bvn[nt] = 0.f;
            if constexpr (HAS_BIAS) {
                int col = nt * 16 + lr;
                if (col < N_OUT) bvn[nt] = bias[g * N_OUT + col];
            }
        }
        #pragma unroll
        for (int p = 0; p < 2; ++p) {
            if ((wid >> 1) == p) {           // waves owning rows p*64..p*64+63
                #pragma unroll
                for (int nt = 0; nt < NT; ++nt) {
                    const int col = nt * 16 + lr;
                    const bool valid = col < N_OUT;
                    #pragma unroll
                    for (int mi = 0; mi < 2; ++mi) {
                        const int rloc = (wid & 1) * 32 + mi * 16 + (lg << 2);
                        #pragma unroll
                        for (int r = 0; r < 4; ++r) {
                            float v = acc[mi][nt][r] + bvn[nt];
                            short hb = cvt_bf16(v);
                            float vq = bfs2f(hb);
                            rs1[nt] += vq; rs2[nt] += vq * vq;
                            if (valid) LH[(rloc + r) * 104 + col] = (unsigned short)hb;
                        }
                    }
                }
            }
            __syncthreads();                 // half-tile parked
            #pragma unroll
            for (int i = 0; i < 7; ++i) {
                int e = t + i * 256;
                if (e < 1600) {
                    int row = e / 25;
                    int c4 = (e - row * 25) * 4;
                    ushort4 v = *reinterpret_cast<const ushort4*>(&LH[row * 104 + c4]);
                    *reinterpret_cast<ushort4*>(
                        Hout + ((size_t)g * B_SZ + m0 + p * 64 + row) * 100 + c4) = v;
                }
            }
            __syncthreads();                 // LH reusable
        }
        // deferred BN stats
        #pragma unroll
        for (int nt = 0; nt < NT; ++nt) {
            float s1 = rs1[nt], s2 = rs2[nt];
            s1 += __shfl_xor(s1, 16); s1 += __shfl_xor(s1, 32);
            s2 += __shfl_xor(s2, 16); s2 += __shfl_xor(s2, 32);
            const int col = nt * 16 + lr;
            if (col < N_OUT && lg == 0) {
                atomicAdd(&ls1[col], s1);
                atomicAdd(&ls2[col], s2);
            }
        }
        __syncthreads();
        if (t < N_OUT) {
            atomicAdd(&ssum[g * N_OUT + t], ls1[t]);
            atomicAdd(&ssq[g * N_OUT + t], ls2[t]);
        }
    } else {
        float* LP = (float*)U;
        #pragma unroll
        for (int p = 0; p < 2; ++p) {
            if ((wid >> 1) == p) {
                #pragma unroll
                for (int mi = 0; mi < 2; ++mi) {
                    const int bl = (wid & 1) * 32 + mi * 16 + lr;   // row in half
                    float dp = 0.f;
                    #pragma unroll
                    for (int nt = 0; nt < NT; ++nt) {
                        const int n0 = nt * 16 + (lg << 2);
                        f32x4 v = acc[mi][nt];
                        if (nt < 3) {
                            float2 w01 = *reinterpret_cast<const float2*>(&ow[g * N_OUT + n0]);
                            float2 w23 = *reinterpret_cast<const float2*>(&ow[g * N_OUT + n0 + 2]);
                            dp += v[0] * w01.x + v[1] * w01.y + v[2] * w23.x + v[3] * w23.y;
                            LP[bl * 52 + n0 + 0] = v[0]; LP[bl * 52 + n0 + 1] = v[1];
                            LP[bl * 52 + n0 + 2] = v[2]; LP[bl * 52 + n0 + 3] = v[3];
                        } else if (lg == 0) {  // n0 = 48: n=48,49 valid
                            float2 w01 = *reinterpret_cast<const float2*>(&ow[g * N_OUT + n0]);
                            dp += v[0] * w01.x + v[1] * w01.y;
                            LP[bl * 52 + n0 + 0] = v[0]; LP[bl * 52 + n0 + 1] = v[1];
                        }
                    }
                    dp += __shfl_xor(dp, 16); dp += __shfl_xor(dp, 32);
                    if (lg == 0) atomicAdd(&out_acc[m0 + p * 64 + bl], dp);
                }
            }
            __syncthreads();
            #pragma unroll
            for (int i = 0; i < 7; ++i) {
                int e = t + i * 256;
                if (e < 1600) {
                    int row = e / 25;
                    int c2 = e - row * 25;
                    float2 v = *reinterpret_cast<const float2*>(&LP[row * 52 + c2 * 2]);
                    *reinterpret_cast<float2*>(
                        &pred[(size_t)(m0 + p * 64 + row) * 5000 + g * N_OUT + c2 * 2]) = v;
                }
            }
            __syncthreads();
        }
    }
}

// BN finalize -> per-channel scale/offset (128-stride, identity pads).
__global__ __launch_bounds__(256) void k_bnfin(const float* __restrict__ ssum,
                                               const float* __restrict__ ssq,
                                               const float* __restrict__ gamma,
                                               const float* __restrict__ beta,
                                               float* __restrict__ sa,
                                               float* __restrict__ sb) {
    int c = blockIdx.x * 256 + threadIdx.x;
    if (c < G_SZ * 128) {
        int g = c >> 7, ch = c & 127;
        float s, o;
        if (ch < 100) {
            float mean = ssum[g * 100 + ch] * (1.f / 8192.f);
            float var = ssq[g * 100 + ch] * (1.f / 8192.f) - mean * mean;
            s = rsqrtf(var + 1e-5f) * gamma[g * 100 + ch];
            o = beta[g * 100 + ch] - mean * s;
        } else { s = 1.f; o = 0.f; }
        sa[c] = s; sb[c] = o;
    }
}

__global__ __launch_bounds__(256) void k_sig(const float* __restrict__ out_acc,
                                             const float* __restrict__ ob,
                                             float* __restrict__ out) {
    int b = blockIdx.x * 256 + threadIdx.x;
    if (b < B_SZ) {
        float v = ob[0] + out_acc[b];
        out[b] = 1.f / (1.f + expf(-v));
    }
}

extern "C" void kernel_launch(void* const* d_in, const int* in_sizes, int n_in,
                              void* d_out, int out_size, void* d_ws, size_t ws_size,
                              hipStream_t stream) {
    const float* x      = (const float*)d_in[0];
    const int*   uf     = (const int*)d_in[1];
    const float* w0     = (const float*)d_in[2];
    const float* b0     = (const float*)d_in[3];
    const float* w1     = (const float*)d_in[4];
    const float* b1     = (const float*)d_in[5];
    const float* w2     = (const float*)d_in[6];
    const float* b2     = (const float*)d_in[7];
    const float* gamma0 = (const float*)d_in[8];
    const float* beta0  = (const float*)d_in[9];
    const float* gamma1 = (const float*)d_in[10];
    const float* beta1  = (const float*)d_in[11];
    const float* ow     = (const float*)d_in[12];
    const float* ob     = (const float*)d_in[13];

    char* ws = (char*)d_ws;
    const size_t AG_BYTES = (size_t)G_SZ * B_SZ * 128 * 2;  // 209,715,200
    unsigned short* Ag = (unsigned short*)ws;
    unsigned short* h1 = Ag;   // row-major [100][8192][100] bf16; aliases Ag
    float* stat = (float*)(ws + AG_BYTES);
    float* sum0    = stat;            // 10000
    float* ssq0    = stat + 10000;
    float* sum1    = stat + 20000;
    float* ssq1    = stat + 30000;
    float* out_acc = stat + 40000;    // 8192  (zeroed region ends at 48192)
    float* sa0     = stat + 48192;    // 12800 each, fully written by bnfin
    float* sb0     = stat + 60992;
    float* sa1     = stat + 73792;
    float* sb1     = stat + 86592;    // ends 99392 floats = 397,568 B

    unsigned short* p0 = (unsigned short*)(ws + AG_BYTES + 397568);
    unsigned short* p1 = p0 + (size_t)179200 * 8;   // 2,867,200 B each
    unsigned short* p2 = p1 + (size_t)179200 * 8;   // p2: 1,638,400 B

    // h0 row-major in d_out's pred region (dead before dense2 writes pred).
    unsigned short* h0 = (unsigned short*)((float*)d_out + B_SZ);
    float* pred = (float*)d_out + B_SZ;
    float* sig  = (float*)d_out;

    hipMemsetAsync(stat, 0, 48192 * sizeof(float), stream);

    k_packW<<<1800, 256, 0, stream>>>(w0, w1, b1, w2, b2, p0, p1, p2);
    k_gather<<<B_SZ / 16, 256, 0, stream>>>(x, uf, Ag);

    // dense0: K=128 in, bias in epilogue
    k_dense<128, 100, 7, false, false, true><<<6400, 256, 0, stream>>>(
        Ag, p0, b0, nullptr, nullptr, h0, nullptr, sum0, ssq0, nullptr, nullptr);
    k_bnfin<<<50, 256, 0, stream>>>(sum0, ssq0, gamma0, beta0, sa0, sb0);

    // dense1: K=100 in (BN+fold), row-major out
    k_dense<100, 100, 7, true, false, false><<<6400, 256, 0, stream>>>(
        h0, p1, nullptr, sa0, sb0, h1, nullptr, sum1, ssq1, nullptr, nullptr);
    k_bnfin<<<50, 256, 0, stream>>>(sum1, ssq1, gamma1, beta1, sa1, sb1);

    // dense2: K=100 in (BN+fold), pred + dot out
    k_dense<100, 50, 4, true, true, false><<<6400, 256, 0, stream>>>(
        h1, p2, nullptr, sa1, sb1, nullptr, pred, nullptr, nullptr, ow, out_acc);

    k_sig<<<32, 256, 0, stream>>>(out_acc, ob, sig);
}